// Round 3
// baseline (314.461 us; speedup 1.0000x reference)
//
#include <hip/hip_runtime.h>
#include <math.h>

// ---------------------------------------------------------------------------
// TopoGAT: 2-layer GAT on MI355X.
// R10: fixed-capacity bucket CSR build; padded CSR with rowptr/rowEnd.
// R5:  gather tables h1/g in bf16 (fp8 ruled out: 32x coarser quantization
//      would push absmax ~0.5 >> 0.085 threshold).
// R7/R12: xform = LDS-tiled GEMM, node-minor staging (conflict-free).
// R14: CSR build — k_bin at BIN_CHUNK=4096; k_fill2 512 threads + uint4
//      count pass; gCursor memset-based.
// R16: agg kernels rewritten to 8-lane x dwordx4 row gathers.
//      k_agg1: one 1KB gather instruction per 8 edges (was 4x dword),
//      weight-lane == compute-lane (zero weight shfls), 16-edge unroll
//      -> 16 rows in flight. k_agg2: gb rows padded 80B->128B (aligned,
//      fetches FEWER bytes than straddling 80B rows) + same mapping;
//      pad lanes (p>=5) accumulate discarded garbage, masked in epilogue.
// R17: fix AGG_FMA macro parameter capture (param `w` shadowed member `.w`,
//      so `u.w` expanded to `u.w1`). Params renamed W_/U_. No other change.
// ---------------------------------------------------------------------------

#define NBUK_MAX 512
#define BIN_CHUNK 4096
#define BUK_CAP 4608

typedef unsigned short ushort_t;

__device__ inline unsigned int f2bf(float f) {  // RNE fp32->bf16
    unsigned int u = __float_as_uint(f);
    u += 0x7FFFu + ((u >> 16) & 1u);
    return u >> 16;
}
__device__ inline float bf_lo(unsigned int u) {
    return __uint_as_float(u << 16);
}
__device__ inline float bf_hi(unsigned int u) {
    return __uint_as_float(u & 0xFFFF0000u);
}
__device__ inline float lrelu_exp(float q) {
    return __expf(q >= 0.f ? q : 0.2f * q);
}

__device__ inline int wave_incl_scan(int v, int lane) {
    #pragma unroll
    for (int ofs = 1; ofs < 64; ofs <<= 1) {
        int t = __shfl_up(v, ofs);
        if (lane >= ofs) v += t;
    }
    return v;
}

// Bin edges into fixed-capacity bucket regions of tmp. One global atomic per
// (block,bucket); packed word = (src<<8) | (dst&255). 16 edges/thread via
// int4 loads; dst stashed in registers across the reservation barrier.
__global__ __launch_bounds__(256) void k_bin(const int* __restrict__ src,
                                             const int* __restrict__ dst,
                                             int* __restrict__ gCursor,
                                             unsigned int* __restrict__ tmp,
                                             int E, int NBUK) {
    __shared__ int lcnt[NBUK_MAX];
    __shared__ int lcur[NBUK_MAX];
    int tid = threadIdx.x;
    int base = blockIdx.x * BIN_CHUNK;
    for (int i = tid; i < NBUK; i += 256) lcnt[i] = 0;
    __syncthreads();
    int d[16];
    #pragma unroll
    for (int q = 0; q < 4; q++) {
        int e = base + q * 1024 + 4 * tid;
        if (e + 3 < E) {
            int4 v = *(const int4*)&dst[e];
            d[4 * q + 0] = v.x; d[4 * q + 1] = v.y;
            d[4 * q + 2] = v.z; d[4 * q + 3] = v.w;
        } else {
            #pragma unroll
            for (int k = 0; k < 4; k++)
                d[4 * q + k] = (e + k < E) ? dst[e + k] : -1;
        }
    }
    #pragma unroll
    for (int k = 0; k < 16; k++)
        if (d[k] >= 0) atomicAdd(&lcnt[d[k] >> 8], 1);
    __syncthreads();
    for (int b = tid; b < NBUK; b += 256) {
        int c = lcnt[b];
        lcur[b] = c ? b * BUK_CAP + atomicAdd(&gCursor[b], c) : 0;
    }
    __syncthreads();
    #pragma unroll
    for (int q = 0; q < 4; q++) {
        int e = base + q * 1024 + 4 * tid;
        int s[4];
        if (e + 3 < E) {
            int4 v = *(const int4*)&src[e];
            s[0] = v.x; s[1] = v.y; s[2] = v.z; s[3] = v.w;
        } else {
            #pragma unroll
            for (int k = 0; k < 4; k++)
                s[k] = (e + k < E) ? src[e + k] : 0;
        }
        #pragma unroll
        for (int k = 0; k < 4; k++) {
            int dd = d[4 * q + k];
            if (dd >= 0) {
                int p = atomicAdd(&lcur[dd >> 8], 1);
                tmp[p] = ((unsigned int)s[k] << 8) | (unsigned int)(dd & 255);
            }
        }
    }
}

// Exact CSR fill within a bucket (padded layout, base = b*BUK_CAP).
// 512 threads; count pass reads tmp as uint4.
__global__ __launch_bounds__(512) void k_fill2(const unsigned int* __restrict__ tmp,
                                               const int* __restrict__ gCursor,
                                               int* __restrict__ rowptr,
                                               int* __restrict__ rowEnd,
                                               int* __restrict__ csr, int N) {
    __shared__ int cnt[256];
    __shared__ int cur[256];
    __shared__ int wsum[4];
    int b = blockIdx.x, tid = threadIdx.x;
    int e0 = b * BUK_CAP;
    int cnt_e = gCursor[b];       // bucket edge count
    int e1 = e0 + cnt_e;
    if (tid < 256) cnt[tid] = 0;
    __syncthreads();
    {   // count pass: uint4 over the bulk (e0 is 16B-aligned: BUK_CAP*4 % 16 == 0)
        int nq = cnt_e >> 2;
        const uint4* t4 = (const uint4*)(tmp + e0);
        for (int q = tid; q < nq; q += 512) {
            uint4 v = t4[q];
            atomicAdd(&cnt[v.x & 255u], 1);
            atomicAdd(&cnt[v.y & 255u], 1);
            atomicAdd(&cnt[v.z & 255u], 1);
            atomicAdd(&cnt[v.w & 255u], 1);
        }
        for (int i = (nq << 2) + tid; i < cnt_e; i += 512)
            atomicAdd(&cnt[tmp[e0 + i] & 255u], 1);
    }
    __syncthreads();
    if (tid < 256) {
        int lane = tid & 63, wv = tid >> 6;
        int v = cnt[tid];
        int incl = wave_incl_scan(v, lane);
        if (lane == 63) wsum[wv] = incl;
        cnt[tid] = incl - v;  // stash exclusive-within-wave
    }
    __syncthreads();
    if (tid < 256) {
        int wv = tid >> 6;
        int woff = 0;
        for (int i = 0; i < wv; i++) woff += wsum[i];
        int excl = woff + cnt[tid];
        int node = b * 256 + tid;
        int start = e0 + excl;
        cur[tid] = start;
        if (node < N) {
            rowptr[node] = start;
        }
    }
    __syncthreads();
    // rowEnd[node] = next start (cur of tid+1) or e1 for the last
    if (tid < 256) {
        int node = b * 256 + tid;
        if (node < N) rowEnd[node] = (tid < 255) ? cur[tid + 1] : e1;
    }
    __syncthreads();
    for (int i = e0 + tid; i < e1; i += 512) {
        unsigned int t = tmp[i];
        int p = atomicAdd(&cur[t & 255u], 1);
        csr[p] = (int)(t >> 8);
    }
}

// h1b[n][64](bf16) = [x[n]|topo[n]] @ W1 ; as1/ad1 from fp32 accumulators.
// Block = 64 nodes x 64 cols GEMM tile, K=136. W1 + xT staged in LDS,
// node-minor (conflict-free transpose writes).
__global__ __launch_bounds__(256) void k_xform1(const float* __restrict__ x,
                                                const float* __restrict__ topo,
                                                const float* __restrict__ W1,
                                                const float* __restrict__ asrc,
                                                const float* __restrict__ adst,
                                                ushort_t* __restrict__ h1b,
                                                float* __restrict__ as1,
                                                float* __restrict__ ad1, int N) {
    __shared__ float XT[136 * 64];  // XT[k][node]
    __shared__ float WS[136 * 64];  // WS[k][col]
    int tid = threadIdx.x;
    int n0 = blockIdx.x * 64;
    {   // stage W1: 8704 floats = 2176 float4 (once per block)
        const float4* W4 = (const float4*)W1;
        float4* WS4 = (float4*)WS;
        for (int i = tid; i < 2176; i += 256) WS4[i] = W4[i];
    }
    {   // stage x transposed, node-minor: i = k4*64 + node
        const float4* x4 = (const float4*)x;
        for (int i = tid; i < 2048; i += 256) {
            int node = i & 63, k4 = i >> 6;
            int gn = n0 + node; if (gn > N - 1) gn = N - 1;
            float4 v = x4[(size_t)gn * 32 + k4];
            int k = k4 * 4;
            XT[(k + 0) * 64 + node] = v.x;
            XT[(k + 1) * 64 + node] = v.y;
            XT[(k + 2) * 64 + node] = v.z;
            XT[(k + 3) * 64 + node] = v.w;
        }
        // topo rows 128..135: i = j4*64 + node, j4 in {0,1}
        const float4* t4 = (const float4*)topo;
        if (tid < 128) {
            int node = tid & 63, j4 = tid >> 6;
            int gn = n0 + node; if (gn > N - 1) gn = N - 1;
            float4 v = t4[(size_t)gn * 2 + j4];
            int k = 128 + j4 * 4;
            XT[(k + 0) * 64 + node] = v.x;
            XT[(k + 1) * 64 + node] = v.y;
            XT[(k + 2) * 64 + node] = v.z;
            XT[(k + 3) * 64 + node] = v.w;
        }
    }
    __syncthreads();
    int ci = tid & 15, ni = tid >> 4;
    int nb = ni * 4, cb = ci * 4;
    float acc[16];
    #pragma unroll
    for (int i = 0; i < 16; i++) acc[i] = 0.f;
    #pragma unroll 4
    for (int k = 0; k < 136; k++) {
        float4 xv = *(const float4*)&XT[k * 64 + nb];
        float4 wv = *(const float4*)&WS[k * 64 + cb];
        acc[0]  = fmaf(xv.x, wv.x, acc[0]);  acc[1]  = fmaf(xv.x, wv.y, acc[1]);
        acc[2]  = fmaf(xv.x, wv.z, acc[2]);  acc[3]  = fmaf(xv.x, wv.w, acc[3]);
        acc[4]  = fmaf(xv.y, wv.x, acc[4]);  acc[5]  = fmaf(xv.y, wv.y, acc[5]);
        acc[6]  = fmaf(xv.y, wv.z, acc[6]);  acc[7]  = fmaf(xv.y, wv.w, acc[7]);
        acc[8]  = fmaf(xv.z, wv.x, acc[8]);  acc[9]  = fmaf(xv.z, wv.y, acc[9]);
        acc[10] = fmaf(xv.z, wv.z, acc[10]); acc[11] = fmaf(xv.z, wv.w, acc[11]);
        acc[12] = fmaf(xv.w, wv.x, acc[12]); acc[13] = fmaf(xv.w, wv.y, acc[13]);
        acc[14] = fmaf(xv.w, wv.z, acc[14]); acc[15] = fmaf(xv.w, wv.w, acc[15]);
    }
    int head = cb >> 3;  // cols cb..cb+3 lie in one head (cb multiple of 4)
    #pragma unroll
    for (int i = 0; i < 4; i++) {
        int n = n0 + nb + i;
        unsigned int p0 = f2bf(acc[i * 4 + 0]) | (f2bf(acc[i * 4 + 1]) << 16);
        unsigned int p1 = f2bf(acc[i * 4 + 2]) | (f2bf(acc[i * 4 + 3]) << 16);
        if (n < N) *(uint2*)&h1b[(size_t)n * 64 + cb] = make_uint2(p0, p1);
        float s = 0.f, d = 0.f;
        #pragma unroll
        for (int j = 0; j < 4; j++) {
            s = fmaf(acc[i * 4 + j], asrc[cb + j], s);
            d = fmaf(acc[i * 4 + j], adst[cb + j], d);
        }
        s += __shfl_xor(s, 1);  // combine the two half-head threads
        d += __shfl_xor(d, 1);
        if ((ci & 1) == 0 && n < N) {
            as1[n * 8 + head] = s;
            ad1[n * 8 + head] = d;
        }
    }
}

// NOTE: parameter names W_/U_ must not collide with vector members .x/.y/.z/.w
#define AGG_FMA(W_, U_)                                           \
    {                                                             \
        acc[0] = fmaf(W_, bf_lo(U_.x), acc[0]);                   \
        acc[1] = fmaf(W_, bf_hi(U_.x), acc[1]);                   \
        acc[2] = fmaf(W_, bf_lo(U_.y), acc[2]);                   \
        acc[3] = fmaf(W_, bf_hi(U_.y), acc[3]);                   \
        acc[4] = fmaf(W_, bf_lo(U_.z), acc[4]);                   \
        acc[5] = fmaf(W_, bf_hi(U_.z), acc[5]);                   \
        acc[6] = fmaf(W_, bf_lo(U_.w), acc[6]);                   \
        acc[7] = fmaf(W_, bf_hi(U_.w), acc[7]);                   \
        z += W_;                                                  \
    }

// Per-dst softmax-weighted aggregation, layer 1 (+ implicit self loop).
// 8 groups x 8 lanes: ONE dwordx4 gather instruction moves 8 full 128B rows.
// lane = (edge_slot<<3)|head: the weight each lane computes from its as1
// gather IS the weight it consumes — zero weight shuffles. 16-edge unroll
// keeps 16 rows in flight.
__global__ __launch_bounds__(256) void k_agg1(const ushort_t* __restrict__ h1b,
                                              const float* __restrict__ as1,
                                              const float* __restrict__ ad1,
                                              const float* __restrict__ b1,
                                              const int* __restrict__ rowptr,
                                              const int* __restrict__ rowEnd,
                                              const int* __restrict__ csr,
                                              float* __restrict__ h2, int N) {
    int tid = threadIdx.x, lane = tid & 63;
    int n = blockIdx.x * 4 + (tid >> 6);
    if (n >= N) return;
    int g = lane >> 3;      // edge slot 0..7
    int head = lane & 7;    // head (cols 8h..8h+7)
    const char* h1c = (const char*)h1b;
    unsigned hoff = (unsigned)head << 4;   // 16B per head block
    float adv = ad1[n * 8 + head];
    float acc[8];
    #pragma unroll
    for (int k = 0; k < 8; k++) acc[k] = 0.f;
    float z = 0.f;
    {   // self loop (group 0 only)
        float w = lrelu_exp(as1[n * 8 + head] + adv);
        if (g == 0) {
            uint4 u = *(const uint4*)(h1c + (((unsigned)n << 7) + hoff));
            acc[0] = w * bf_lo(u.x); acc[1] = w * bf_hi(u.x);
            acc[2] = w * bf_lo(u.y); acc[3] = w * bf_hi(u.y);
            acc[4] = w * bf_lo(u.z); acc[5] = w * bf_hi(u.z);
            acc[6] = w * bf_lo(u.w); acc[7] = w * bf_hi(u.w);
            z = w;
        }
    }
    int j = rowptr[n], j1 = rowEnd[n];
    for (; j + 16 <= j1; j += 16) {   // 16 rows in flight
        int cv = csr[j + (lane & 15)];
        int se0 = __shfl(cv, g);
        int se1 = __shfl(cv, 8 + g);
        float av0 = as1[se0 * 8 + head];
        float av1 = as1[se1 * 8 + head];
        uint4 u0 = *(const uint4*)(h1c + (((unsigned)se0 << 7) + hoff));
        uint4 u1 = *(const uint4*)(h1c + (((unsigned)se1 << 7) + hoff));
        float w0 = lrelu_exp(av0 + adv);
        float w1 = lrelu_exp(av1 + adv);
        AGG_FMA(w0, u0);
        AGG_FMA(w1, u1);
    }
    if (j + 8 <= j1) {
        int cv = csr[j + (lane & 7)];
        int se = __shfl(cv, g);
        float av = as1[se * 8 + head];
        uint4 u = *(const uint4*)(h1c + (((unsigned)se << 7) + hoff));
        float w = lrelu_exp(av + adv);
        AGG_FMA(w, u);
        j += 8;
    }
    int t = j1 - j;
    if (t > 0) {  // masked tail: clamped index, zeroed weights
        int idx = (lane & 7); idx = idx < t ? idx : t - 1;
        int cv = csr[j + idx];
        int ge = g < t ? g : t - 1;
        int se = __shfl(cv, ge);
        float w = (g < t) ? lrelu_exp(as1[se * 8 + head] + adv) : 0.f;
        uint4 u = *(const uint4*)(h1c + (((unsigned)se << 7) + hoff));
        AGG_FMA(w, u);
    }
    // reduce across the 8 edge-slot groups (lanes differing in bits 3..5)
    #pragma unroll
    for (int k = 0; k < 8; k++) {
        acc[k] += __shfl_xor(acc[k], 8);
        acc[k] += __shfl_xor(acc[k], 16);
        acc[k] += __shfl_xor(acc[k], 32);
    }
    z += __shfl_xor(z, 8); z += __shfl_xor(z, 16); z += __shfl_xor(z, 32);
    if (g == 0) {
        float inv = 1.f / (z + 1e-16f);
        float o[8];
        #pragma unroll
        for (int k = 0; k < 8; k++) {
            float v = acc[k] * inv + b1[head * 8 + k];
            o[k] = v > 0.f ? v : (__expf(v) - 1.f);
        }
        float4* dp = (float4*)&h2[(size_t)n * 64 + head * 8];
        dp[0] = make_float4(o[0], o[1], o[2], o[3]);
        dp[1] = make_float4(o[4], o[5], o[6], o[7]);
    }
}

// gb[n][64-padded](bf16) = h2[n] @ W2 (cols 0..39 valid); as2/ad2 fp32.
// Block = 64 nodes x 40 cols GEMM tile, K=64. Node-minor staging.
__global__ __launch_bounds__(256) void k_xform2(const float* __restrict__ h2,
                                                const float* __restrict__ W2,
                                                const float* __restrict__ asrc2,
                                                const float* __restrict__ adst2,
                                                ushort_t* __restrict__ gb,
                                                float* __restrict__ as2,
                                                float* __restrict__ ad2, int N) {
    __shared__ float XT[64 * 64];  // h2T[k][node]
    __shared__ float WS[64 * 40];  // WS[k][col]
    int tid = threadIdx.x;
    int n0 = blockIdx.x * 64;
    {   // stage W2: 2560 floats = 640 float4
        const float4* W4 = (const float4*)W2;
        float4* WS4 = (float4*)WS;
        for (int i = tid; i < 640; i += 256) WS4[i] = W4[i];
    }
    {   // stage h2 transposed, node-minor: i = k4*64 + node
        const float4* h4 = (const float4*)h2;
        for (int i = tid; i < 1024; i += 256) {
            int node = i & 63, k4 = i >> 6;
            int gn = n0 + node; if (gn > N - 1) gn = N - 1;
            float4 v = h4[(size_t)gn * 16 + k4];
            int k = k4 * 4;
            XT[(k + 0) * 64 + node] = v.x;
            XT[(k + 1) * 64 + node] = v.y;
            XT[(k + 2) * 64 + node] = v.z;
            XT[(k + 3) * 64 + node] = v.w;
        }
    }
    __syncthreads();
    int ci = tid & 15, ni = tid >> 4;
    int nb = ni * 4, cb = ci * 4;
    float acc[16];
    #pragma unroll
    for (int i = 0; i < 16; i++) acc[i] = 0.f;
    if (ci < 10) {
        #pragma unroll 4
        for (int k = 0; k < 64; k++) {
            float4 xv = *(const float4*)&XT[k * 64 + nb];
            float4 wv = *(const float4*)&WS[k * 40 + cb];
            acc[0]  = fmaf(xv.x, wv.x, acc[0]);  acc[1]  = fmaf(xv.x, wv.y, acc[1]);
            acc[2]  = fmaf(xv.x, wv.z, acc[2]);  acc[3]  = fmaf(xv.x, wv.w, acc[3]);
            acc[4]  = fmaf(xv.y, wv.x, acc[4]);  acc[5]  = fmaf(xv.y, wv.y, acc[5]);
            acc[6]  = fmaf(xv.y, wv.z, acc[6]);  acc[7]  = fmaf(xv.y, wv.w, acc[7]);
            acc[8]  = fmaf(xv.z, wv.x, acc[8]);  acc[9]  = fmaf(xv.z, wv.y, acc[9]);
            acc[10] = fmaf(xv.z, wv.z, acc[10]); acc[11] = fmaf(xv.z, wv.w, acc[11]);
            acc[12] = fmaf(xv.w, wv.x, acc[12]); acc[13] = fmaf(xv.w, wv.y, acc[13]);
            acc[14] = fmaf(xv.w, wv.z, acc[14]); acc[15] = fmaf(xv.w, wv.w, acc[15]);
        }
    }
    #pragma unroll
    for (int i = 0; i < 4; i++) {
        int n = n0 + nb + i;
        if (ci < 10 && n < N) {
            unsigned int p0 = f2bf(acc[i * 4 + 0]) | (f2bf(acc[i * 4 + 1]) << 16);
            unsigned int p1 = f2bf(acc[i * 4 + 2]) | (f2bf(acc[i * 4 + 3]) << 16);
            *(uint2*)&gb[(size_t)n * 64 + cb] = make_uint2(p0, p1);  // 128B rows
        }
        float s = 0.f, d = 0.f;
        if (ci < 10) {
            #pragma unroll
            for (int j = 0; j < 4; j++) {
                s = fmaf(acc[i * 4 + j], asrc2[cb + j], s);
                d = fmaf(acc[i * 4 + j], adst2[cb + j], d);
            }
        }
        // reduce over the 16-lane ci group (ci>=10 contribute 0)
        s += __shfl_xor(s, 1); s += __shfl_xor(s, 2);
        s += __shfl_xor(s, 4); s += __shfl_xor(s, 8);
        d += __shfl_xor(d, 1); d += __shfl_xor(d, 2);
        d += __shfl_xor(d, 4); d += __shfl_xor(d, 8);
        if (ci == 0 && n < N) { as2[n] = s; ad2[n] = d; }
    }
}

// Layer-2 aggregation + bias + log_softmax. Same 8x8 mapping as k_agg1 on
// 128B-padded gb rows; lanes p>=5 gather pad garbage into discarded accs.
__global__ __launch_bounds__(256) void k_agg2(const ushort_t* __restrict__ gb,
                                              const float* __restrict__ as2,
                                              const float* __restrict__ ad2,
                                              const float* __restrict__ b2,
                                              const int* __restrict__ rowptr,
                                              const int* __restrict__ rowEnd,
                                              const int* __restrict__ csr,
                                              float* __restrict__ out, int N) {
    int tid = threadIdx.x, lane = tid & 63;
    int n = blockIdx.x * 4 + (tid >> 6);
    if (n >= N) return;
    int g = lane >> 3;    // edge slot 0..7
    int p = lane & 7;     // col block (8p..8p+7), p<5 real
    const char* gbc = (const char*)gb;
    unsigned poff = (unsigned)p << 4;
    float add = ad2[n];
    float acc[8];
    #pragma unroll
    for (int k = 0; k < 8; k++) acc[k] = 0.f;
    float z = 0.f;
    {   // self loop (group 0 only)
        float w = lrelu_exp(as2[n] + add);
        if (g == 0) {
            uint4 u = *(const uint4*)(gbc + (((unsigned)n << 7) + poff));
            acc[0] = w * bf_lo(u.x); acc[1] = w * bf_hi(u.x);
            acc[2] = w * bf_lo(u.y); acc[3] = w * bf_hi(u.y);
            acc[4] = w * bf_lo(u.z); acc[5] = w * bf_hi(u.z);
            acc[6] = w * bf_lo(u.w); acc[7] = w * bf_hi(u.w);
            z = w;
        }
    }
    int j = rowptr[n], j1 = rowEnd[n];
    for (; j + 16 <= j1; j += 16) {
        int cv = csr[j + (lane & 15)];
        int se0 = __shfl(cv, g);
        int se1 = __shfl(cv, 8 + g);
        float av0 = as2[se0];
        float av1 = as2[se1];
        uint4 u0 = *(const uint4*)(gbc + (((unsigned)se0 << 7) + poff));
        uint4 u1 = *(const uint4*)(gbc + (((unsigned)se1 << 7) + poff));
        float w0 = lrelu_exp(av0 + add);
        float w1 = lrelu_exp(av1 + add);
        AGG_FMA(w0, u0);
        AGG_FMA(w1, u1);
    }
    if (j + 8 <= j1) {
        int cv = csr[j + (lane & 7)];
        int se = __shfl(cv, g);
        float av = as2[se];
        uint4 u = *(const uint4*)(gbc + (((unsigned)se << 7) + poff));
        float w = lrelu_exp(av + add);
        AGG_FMA(w, u);
        j += 8;
    }
    int t = j1 - j;
    if (t > 0) {
        int idx = (lane & 7); idx = idx < t ? idx : t - 1;
        int cv = csr[j + idx];
        int ge = g < t ? g : t - 1;
        int se = __shfl(cv, ge);
        float w = (g < t) ? lrelu_exp(as2[se] + add) : 0.f;
        uint4 u = *(const uint4*)(gbc + (((unsigned)se << 7) + poff));
        AGG_FMA(w, u);
    }
    #pragma unroll
    for (int k = 0; k < 8; k++) {
        acc[k] += __shfl_xor(acc[k], 8);
        acc[k] += __shfl_xor(acc[k], 16);
        acc[k] += __shfl_xor(acc[k], 32);
    }
    z += __shfl_xor(z, 8); z += __shfl_xor(z, 16); z += __shfl_xor(z, 32);
    if (g == 0) {  // lanes 0..7; p==lane; p<5 hold the 40 logits
        bool act = (p < 5);
        float inv = 1.f / (z + 1e-16f);
        float l[8];
        float mv = -INFINITY;
        if (act) {
            #pragma unroll
            for (int k = 0; k < 8; k++) {
                l[k] = acc[k] * inv + b2[p * 8 + k];
                mv = fmaxf(mv, l[k]);
            }
        }
        mv = fmaxf(mv, __shfl_xor(mv, 1));
        mv = fmaxf(mv, __shfl_xor(mv, 2));
        mv = fmaxf(mv, __shfl_xor(mv, 4));
        float ev = 0.f;
        if (act) {
            #pragma unroll
            for (int k = 0; k < 8; k++) ev += __expf(l[k] - mv);
        }
        ev += __shfl_xor(ev, 1);
        ev += __shfl_xor(ev, 2);
        ev += __shfl_xor(ev, 4);
        if (act) {
            float ls = mv + __logf(ev);
            float4* dp = (float4*)&out[(size_t)n * 40 + p * 8];
            dp[0] = make_float4(l[0] - ls, l[1] - ls, l[2] - ls, l[3] - ls);
            dp[1] = make_float4(l[4] - ls, l[5] - ls, l[6] - ls, l[7] - ls);
        }
    }
}

extern "C" void kernel_launch(void* const* d_in, const int* in_sizes, int n_in,
                              void* d_out, int out_size, void* d_ws, size_t ws_size,
                              hipStream_t stream) {
    const float* x    = (const float*)d_in[0];
    const float* topo = (const float*)d_in[1];
    const int*   ei   = (const int*)d_in[2];
    const float* W1   = (const float*)d_in[3];
    const float* a_s1 = (const float*)d_in[4];
    const float* a_d1 = (const float*)d_in[5];
    const float* b1   = (const float*)d_in[6];
    const float* W2   = (const float*)d_in[7];
    const float* a_s2 = (const float*)d_in[8];
    const float* a_d2 = (const float*)d_in[9];
    const float* b2   = (const float*)d_in[10];
    float* out = (float*)d_out;

    int N = in_sizes[0] / 128;
    int E = in_sizes[2] / 2;
    const int* esrc = ei;
    const int* edst = ei + E;
    int NBUK = (N + 255) / 256;
    size_t cap = (size_t)NBUK * BUK_CAP;

    char* ws = (char*)d_ws;
    size_t off = 0;
    auto alloc = [&](size_t bytes) -> void* {
        void* p = ws + off;
        off = (off + bytes + 255) & ~(size_t)255;
        return p;
    };
    ushort_t* h1b  = (ushort_t*)alloc((size_t)N * 64 * 2);
    float* as1     = (float*)alloc((size_t)N * 8 * 4);
    float* ad1     = (float*)alloc((size_t)N * 8 * 4);
    float* h2      = (float*)alloc((size_t)N * 64 * 4);
    ushort_t* gb   = (ushort_t*)alloc((size_t)N * 64 * 2);  // 128B padded rows
    float* as2     = (float*)alloc((size_t)N * 4);
    float* ad2     = (float*)alloc((size_t)N * 4);
    int*   rowptr  = (int*)alloc((size_t)N * 4);
    int*   rowEnd  = (int*)alloc((size_t)N * 4);
    int*   csr     = (int*)alloc(cap * 4);
    unsigned int* tmp = (unsigned int*)alloc(cap * 4);
    int* gCursor   = (int*)alloc((size_t)NBUK * 4);

    hipMemsetAsync(gCursor, 0, (size_t)NBUK * 4, stream);  // count-based cursors
    int nbin = (E + BIN_CHUNK - 1) / BIN_CHUNK;
    k_bin<<<nbin, 256, 0, stream>>>(esrc, edst, gCursor, tmp, E, NBUK);
    k_fill2<<<NBUK, 512, 0, stream>>>(tmp, gCursor, rowptr, rowEnd, csr, N);

    int nbg = (N + 63) / 64;  // 64-node GEMM tiles
    int nb4 = (N + 3) / 4;    // 1 node/wave x 4 waves/block
    k_xform1<<<nbg, 256, 0, stream>>>(x, topo, W1, a_s1, a_d1, h1b, as1, ad1, N);
    k_agg1<<<nb4, 256, 0, stream>>>(h1b, as1, ad1, b1, rowptr, rowEnd, csr, h2, N);
    k_xform2<<<nbg, 256, 0, stream>>>(h2, W2, a_s2, a_d2, gb, as2, ad2, N);
    k_agg2<<<nb4, 256, 0, stream>>>(gb, as2, ad2, b2, rowptr, rowEnd, csr, out, N);
}